// Round 2
// baseline (9803.354 us; speedup 1.0000x reference)
//
#include <hip/hip_runtime.h>
#include <hip/hip_bf16.h>
#include <stdint.h>

typedef __bf16 bf16_t;
typedef bf16_t bf16x8 __attribute__((ext_vector_type(8)));
typedef float  f32x4  __attribute__((ext_vector_type(4)));
typedef float  f32x16 __attribute__((ext_vector_type(16)));

#define I_DIM 512
#define H_DIM 1024
#define B_DIM 64
#define S_DIM 512
#define G4    4096   // 4*H
#define CHUNK 32     // steps per chunk
#define NCHUNK (S_DIM / CHUNK)

// ---------------- workspace layout (bytes) — total ~29 MB ----------------
#define O_WXT   0x0000000ULL  // [4096][512]  bf16 = 4 MB
#define O_WHT   0x0400000ULL  // [4096][1024] bf16 = 8 MB
#define O_BIAS  0x0C00000ULL  // [4096] f32 = 16 KB
#define O_HBUF  0x0C10000ULL  // 2 * [64][1024] bf16 = 256 KB
#define O_CST   0x0C50000ULL  // [64][1024] f32 = 256 KB
#define O_FLAGS 0x0C90000ULL  // 256 * u32 = 1 KB
#define O_XP    0x0D00000ULL  // [CHUNK*64][4096] bf16 = 16 MB

__device__ __forceinline__ float sigm(float x)      { return 1.f / (1.f + __expf(-x)); }
__device__ __forceinline__ float tanh_fast(float x) { return 1.f - 2.f / (__expf(2.f * x) + 1.f); }

// Packed gate-column permutation: packed col p = q*32 + g*8 + jj  <->  hidden j = q*8+jj, gate g (0:i 1:f 2:g 3:o)

__global__ void k_pack_wx(const float* __restrict__ w0, const float* __restrict__ w1,
                          const float* __restrict__ w2, const float* __restrict__ w3,
                          bf16_t* __restrict__ wxt) {
    int tid = blockIdx.x * 256 + threadIdx.x;   // 4096*512 threads
    int k = tid >> 12;                          // 0..511
    int p = tid & 4095;
    int q = p >> 5, g = (p >> 3) & 3, jj = p & 7;
    int j = q * 8 + jj;
    const float* src = (g == 0) ? w0 : (g == 1) ? w1 : (g == 2) ? w2 : w3;
    wxt[(size_t)p * I_DIM + k] = (bf16_t)src[k * H_DIM + j];
}

__global__ void k_pack_wh(const float* __restrict__ w0, const float* __restrict__ w1,
                          const float* __restrict__ w2, const float* __restrict__ w3,
                          bf16_t* __restrict__ wht) {
    int tid = blockIdx.x * 256 + threadIdx.x;   // 4096*1024 threads
    int k = tid >> 12;                          // 0..1023
    int p = tid & 4095;
    int q = p >> 5, g = (p >> 3) & 3, jj = p & 7;
    int j = q * 8 + jj;
    const float* src = (g == 0) ? w0 : (g == 1) ? w1 : (g == 2) ? w2 : w3;
    wht[(size_t)p * H_DIM + k] = (bf16_t)src[k * H_DIM + j];
}

__global__ void k_pack_bias(const float* bi0, const float* bh0, const float* bi1, const float* bh1,
                            const float* bi2, const float* bh2, const float* bi3, const float* bh3,
                            float* __restrict__ bias) {
    int p = blockIdx.x * 256 + threadIdx.x;
    int q = p >> 5, g = (p >> 3) & 3, jj = p & 7;
    int j = q * 8 + jj;
    const float* a = (g == 0) ? bi0 : (g == 1) ? bi1 : (g == 2) ? bi2 : bi3;
    const float* b = (g == 0) ? bh0 : (g == 1) ? bh1 : (g == 2) ? bh2 : bh3;
    bias[p] = a[j] + b[j];
}

// ---------------- chunked x_proj GEMM ----------------
// rows r = s*64 + b for s in [t0, t0+CHUNK); xp chunk-local. 128x128 tile, 256 thr (2x2 waves), BK=32.
// grid: x = col tile (32), y = row tile (CHUNK*64/128 = 16)
__global__ __launch_bounds__(256, 2) void k_xproj(
    const float* __restrict__ x, const bf16_t* __restrict__ wxt,
    const float* __restrict__ bias, bf16_t* __restrict__ xp, int r_base)
{
    __shared__ __align__(16) bf16_t Al[8 * 64 * 8];  // 8 KB, frag order
    __shared__ __align__(16) bf16_t Bl[8 * 64 * 8];
    const int tid = threadIdx.x;
    const int n0 = blockIdx.x * 128;            // packed col tile
    const int r0 = r_base + blockIdx.y * 128;   // global output row tile
    const int wv = tid >> 6;
    const int lane = tid & 63;
    const int mq = wv >> 1, nq = wv & 1;
    f32x4 acc[4][4] = {};

    for (int kk = 0; kk < I_DIM; kk += 32) {
        __syncthreads();
        #pragma unroll
        for (int sidx = 0; sidx < 2; ++sidx) {
            int s = tid + sidx * 256;          // 0..511
            int mt = s >> 6, l = s & 63;
            int m = l & 15, kb = (l >> 4) * 8;
            int r = r0 + mt * 16 + m;
            int b = r & 63, si = r >> 6;
            const float* gp = x + ((size_t)(b * S_DIM + si)) * I_DIM + kk + kb;
            float4 v0 = *(const float4*)gp;
            float4 v1 = *(const float4*)(gp + 4);
            bf16x8 a;
            a[0] = (bf16_t)v0.x; a[1] = (bf16_t)v0.y; a[2] = (bf16_t)v0.z; a[3] = (bf16_t)v0.w;
            a[4] = (bf16_t)v1.x; a[5] = (bf16_t)v1.y; a[6] = (bf16_t)v1.z; a[7] = (bf16_t)v1.w;
            *(bf16x8*)&Al[s * 8] = a;
            bf16x8 bv = *(const bf16x8*)(wxt + (size_t)(n0 + mt * 16 + m) * I_DIM + kk + kb);
            *(bf16x8*)&Bl[s * 8] = bv;
        }
        __syncthreads();
        bf16x8 af[4], bfr[4];
        #pragma unroll
        for (int mt = 0; mt < 4; ++mt) af[mt]  = *(bf16x8*)&Al[((mq * 4 + mt) * 64 + lane) * 8];
        #pragma unroll
        for (int nt = 0; nt < 4; ++nt) bfr[nt] = *(bf16x8*)&Bl[((nq * 4 + nt) * 64 + lane) * 8];
        #pragma unroll
        for (int mt = 0; mt < 4; ++mt)
            #pragma unroll
            for (int nt = 0; nt < 4; ++nt)
                acc[mt][nt] = __builtin_amdgcn_mfma_f32_16x16x32_bf16(af[mt], bfr[nt], acc[mt][nt], 0, 0, 0);
    }
    const int l15 = lane & 15, quad = lane >> 4;
    #pragma unroll
    for (int nt = 0; nt < 4; ++nt) {
        int col = n0 + nq * 64 + nt * 16 + l15;
        float bv = bias[col];
        #pragma unroll
        for (int mt = 0; mt < 4; ++mt)
            #pragma unroll
            for (int r = 0; r < 4; ++r) {
                int row = r0 - r_base + mq * 64 + mt * 16 + quad * 4 + r;  // chunk-local
                xp[(size_t)row * G4 + col] = (bf16_t)(acc[mt][nt][r] + bv);
            }
    }
}

// ---------------- persistent recurrent kernel (one chunk of CHUNK steps) ----------------
// 256 WGs x 64 thr. WG wg: q = wg>>1 (8 hidden units = 32 packed cols), bh = wg&1 (batch half).
// Flag-array barrier: WG i release-stores t+1 to flags[i]; all poll 256 flags (4 coalesced
// agent loads/lane + __all). Bounded spin: residency failure -> wrong answer, not a hang.
__global__ __launch_bounds__(64, 1) void k_lstm(
    const bf16_t* __restrict__ wht, const bf16_t* __restrict__ xp,
    bf16_t* __restrict__ hbuf, float* __restrict__ cstbuf,
    float* __restrict__ out, unsigned* __restrict__ flags, int t0)
{
    __shared__ __align__(16) bf16_t Blds[32768];   // 64 KB B-fragments [ks(64)][lane(64)][8]
    const int lane = threadIdx.x;
    const int wg = blockIdx.x;
    const int q  = wg >> 1;
    const int bh = wg & 1;

    // Stage WhT rows q*32..+31 into LDS in 32x32x16 B-fragment order:
    // element (c,k): ks=k>>4, half=(k>>3)&1 -> Blds[((ks*64) + c + 32*half)*8 + (k&7)]
    for (int i = 0; i < 64; ++i) {
        int task = lane + (i << 6);          // 0..4095 = 32 c x 128 k-runs
        int c = task >> 7;
        int k = (task & 127) << 3;
        bf16x8 v = *(const bf16x8*)(wht + (((size_t)(q * 32 + c)) << 10) + k);
        int base = (((k >> 4) << 6) + c + (((k >> 3) & 1) << 5)) << 3;
        *(bf16x8*)&Blds[base] = v;
    }
    __syncthreads();

    const int col  = lane & 31;        // packed col within slice; also A-row index
    const int ksel = lane >> 5;        // k-half selector
    const int gt   = (lane >> 3) & 3;  // 0:i 1:f 2:g 3:o
    const int arow = bh * 32 + col;    // h row this lane loads (A operand)
    const int jj   = lane & 7;

    int rrow[16];
    #pragma unroll
    for (int r = 0; r < 16; ++r) rrow[r] = (r & 3) + 8 * (r >> 2) + 4 * ksel;  // 32x32 C/D row map

    float cst[16];
    if (t0 == 0) {
        #pragma unroll
        for (int r = 0; r < 16; ++r) cst[r] = 0.f;
    } else {
        #pragma unroll
        for (int r = 0; r < 16; ++r)
            cst[r] = cstbuf[(bh * 32 + rrow[r]) * H_DIM + q * 8 + jj];
    }

    // prefetch xp for first local step
    bf16_t xpr[16];
    #pragma unroll
    for (int r = 0; r < 16; ++r)
        xpr[r] = xp[(size_t)(bh * 32 + rrow[r]) * G4 + q * 32 + col];

    for (int tl = 0; tl < CHUNK; ++tl) {
        const int t = t0 + tl;
        const bf16_t* hb = hbuf + ((t & 1) << 16);
        const bf16_t* ab = hb + (size_t)arow * H_DIM + ksel * 8;
        f32x16 acc0 = {}, acc1 = {}, acc2 = {}, acc3 = {};
        #pragma unroll
        for (int ks = 0; ks < 64; ks += 4) {
            bf16x8 a0 = *(const bf16x8*)(ab + (ks + 0) * 16);
            bf16x8 a1 = *(const bf16x8*)(ab + (ks + 1) * 16);
            bf16x8 a2 = *(const bf16x8*)(ab + (ks + 2) * 16);
            bf16x8 a3 = *(const bf16x8*)(ab + (ks + 3) * 16);
            bf16x8 b0 = *(const bf16x8*)&Blds[(((ks + 0) << 6) + lane) << 3];
            bf16x8 b1 = *(const bf16x8*)&Blds[(((ks + 1) << 6) + lane) << 3];
            bf16x8 b2 = *(const bf16x8*)&Blds[(((ks + 2) << 6) + lane) << 3];
            bf16x8 b3 = *(const bf16x8*)&Blds[(((ks + 3) << 6) + lane) << 3];
            acc0 = __builtin_amdgcn_mfma_f32_32x32x16_bf16(a0, b0, acc0, 0, 0, 0);
            acc1 = __builtin_amdgcn_mfma_f32_32x32x16_bf16(a1, b1, acc1, 0, 0, 0);
            acc2 = __builtin_amdgcn_mfma_f32_32x32x16_bf16(a2, b2, acc2, 0, 0, 0);
            acc3 = __builtin_amdgcn_mfma_f32_32x32x16_bf16(a3, b3, acc3, 0, 0, 0);
        }
        f32x16 accs = acc0 + acc1 + acc2 + acc3;

        float act[16];
        #pragma unroll
        for (int r = 0; r < 16; ++r) {
            float pre = accs[r] + (float)xpr[r];
            act[r] = (gt == 2) ? tanh_fast(pre) : sigm(pre);
        }

        // prefetch next local step's xp (rides through barrier in regs)
        int tln = (tl < CHUNK - 1) ? tl + 1 : tl;
        #pragma unroll
        for (int r = 0; r < 16; ++r)
            xpr[r] = xp[(size_t)(tln * 64 + bh * 32 + rrow[r]) * G4 + q * 32 + col];

        bf16_t* hn = hbuf + (((t + 1) & 1) << 16);
        #pragma unroll
        for (int r = 0; r < 16; ++r) {
            float fv = __shfl_xor(act[r], 8, 64);
            float gv = __shfl_xor(act[r], 16, 64);
            float ov = __shfl_xor(act[r], 24, 64);
            if (gt == 0) {
                float cn = fv * cst[r] + act[r] * gv;
                cst[r] = cn;
                float hv = ov * tanh_fast(cn);
                int rowg = bh * 32 + rrow[r];
                int j = q * 8 + jj;
                hn[rowg * H_DIM + j] = (bf16_t)hv;
                if (t == S_DIM - 1) {
                    out[rowg * H_DIM + j] = hv;            // h_T
                    out[65536 + rowg * H_DIM + j] = cn;    // c_T
                }
            }
        }

        if (tl < CHUNK - 1) {
            unsigned tv = (unsigned)(t + 1);
            __builtin_amdgcn_fence(__ATOMIC_RELEASE, "agent");   // flush h stores to LLC
            __hip_atomic_store(&flags[wg], tv, __ATOMIC_RELAXED, __HIP_MEMORY_SCOPE_AGENT);
            int guard = 200000;
            for (;;) {
                unsigned f0 = __hip_atomic_load(&flags[lane],       __ATOMIC_RELAXED, __HIP_MEMORY_SCOPE_AGENT);
                unsigned f1 = __hip_atomic_load(&flags[lane + 64],  __ATOMIC_RELAXED, __HIP_MEMORY_SCOPE_AGENT);
                unsigned f2 = __hip_atomic_load(&flags[lane + 128], __ATOMIC_RELAXED, __HIP_MEMORY_SCOPE_AGENT);
                unsigned f3 = __hip_atomic_load(&flags[lane + 192], __ATOMIC_RELAXED, __HIP_MEMORY_SCOPE_AGENT);
                int ok = (f0 >= tv) && (f1 >= tv) && (f2 >= tv) && (f3 >= tv);
                if (__all(ok) || --guard == 0) break;
                __builtin_amdgcn_s_sleep(1);
            }
            __builtin_amdgcn_fence(__ATOMIC_ACQUIRE, "agent");   // invalidate L1/L2 -> fresh h
        }
    }

    // persist c-state for next chunk
    if (gt == 0) {
        #pragma unroll
        for (int r = 0; r < 16; ++r)
            cstbuf[(bh * 32 + rrow[r]) * H_DIM + q * 8 + jj] = cst[r];
    }
}

extern "C" void kernel_launch(void* const* d_in, const int* in_sizes, int n_in,
                              void* d_out, int out_size, void* d_ws, size_t ws_size,
                              hipStream_t stream) {
    const float* x   = (const float*)d_in[0];
    const float* wii = (const float*)d_in[1];
    const float* bii = (const float*)d_in[2];
    const float* whi = (const float*)d_in[3];
    const float* bhi = (const float*)d_in[4];
    const float* wif = (const float*)d_in[5];
    const float* bif = (const float*)d_in[6];
    const float* whf = (const float*)d_in[7];
    const float* bhf = (const float*)d_in[8];
    const float* wig = (const float*)d_in[9];
    const float* big = (const float*)d_in[10];
    const float* whg = (const float*)d_in[11];
    const float* bhg = (const float*)d_in[12];
    const float* wio = (const float*)d_in[13];
    const float* bio = (const float*)d_in[14];
    const float* who = (const float*)d_in[15];
    const float* bho = (const float*)d_in[16];

    char* ws = (char*)d_ws;
    bf16_t*  wxt   = (bf16_t*)(ws + O_WXT);
    bf16_t*  wht   = (bf16_t*)(ws + O_WHT);
    float*   bias  = (float*)(ws + O_BIAS);
    bf16_t*  hbuf  = (bf16_t*)(ws + O_HBUF);
    float*   cstb  = (float*)(ws + O_CST);
    unsigned* flags = (unsigned*)(ws + O_FLAGS);
    bf16_t*  xp    = (bf16_t*)(ws + O_XP);

    hipMemsetAsync(hbuf, 0, 2 * 64 * 1024 * sizeof(bf16_t), stream);
    hipMemsetAsync(flags, 0, 256 * sizeof(unsigned), stream);

    k_pack_wx<<<8192, 256, 0, stream>>>(wii, wif, wig, wio, wxt);
    k_pack_wh<<<16384, 256, 0, stream>>>(whi, whf, whg, who, wht);
    k_pack_bias<<<16, 256, 0, stream>>>(bii, bhi, bif, bhf, big, bhg, bio, bho, bias);

    for (int c = 0; c < NCHUNK; ++c) {
        k_xproj<<<dim3(32, CHUNK * 64 / 128), 256, 0, stream>>>(x, wxt, bias, xp, c * CHUNK * 64);
        k_lstm<<<256, 64, 0, stream>>>(wht, xp, hbuf, cstb, (float*)d_out, flags, c * CHUNK);
    }
}

// Round 3
// 7516.084 us; speedup vs baseline: 1.3043x; 1.3043x over previous
//
#include <hip/hip_runtime.h>
#include <hip/hip_bf16.h>
#include <stdint.h>

typedef __bf16 bf16_t;
typedef bf16_t bf16x8 __attribute__((ext_vector_type(8)));
typedef float  f32x4  __attribute__((ext_vector_type(4)));
typedef float  f32x16 __attribute__((ext_vector_type(16)));
typedef uint64_t u64x2 __attribute__((ext_vector_type(2)));

#define I_DIM 512
#define H_DIM 1024
#define B_DIM 64
#define S_DIM 512
#define G4    4096   // 4*H
#define CHUNK 32     // steps per chunk
#define NCHUNK (S_DIM / CHUNK)

// ---------------- workspace layout (bytes) — total ~29 MB ----------------
#define O_WXT   0x0000000ULL  // [4096][512]  bf16 = 4 MB
#define O_WHT   0x0400000ULL  // [4096][1024] bf16 = 8 MB
#define O_BIAS  0x0C00000ULL  // [4096] f32 = 16 KB
#define O_HBUF  0x0C10000ULL  // 2 * [64][1024] bf16 = 256 KB
#define O_CST   0x0C50000ULL  // [64][1024] f32 = 256 KB
#define O_FLAGS 0x0C90000ULL  // 256 * u32 = 1 KB
#define O_XP    0x0D00000ULL  // [CHUNK*64][4096] bf16 = 16 MB

__device__ __forceinline__ float sigm(float x)      { return 1.f / (1.f + __expf(-x)); }
__device__ __forceinline__ float tanh_fast(float x) { return 1.f - 2.f / (__expf(2.f * x) + 1.f); }

// LLC-coherent primitives: no wbl2/inv anywhere — each op is individually
// write-through / cache-bypassing via sc0 sc1 (agent-scope atomics).
__device__ __forceinline__ uint64_t ld_u64_llc(const uint64_t* p) {
    return __hip_atomic_load(p, __ATOMIC_RELAXED, __HIP_MEMORY_SCOPE_AGENT);
}
__device__ __forceinline__ void st_u32_llc(uint32_t* p, uint32_t v) {
    __hip_atomic_store(p, v, __ATOMIC_RELAXED, __HIP_MEMORY_SCOPE_AGENT);
}

// Packed gate-column permutation: packed col p = q*32 + g*8 + jj  <->  hidden j = q*8+jj, gate g (0:i 1:f 2:g 3:o)

__global__ void k_pack_wx(const float* __restrict__ w0, const float* __restrict__ w1,
                          const float* __restrict__ w2, const float* __restrict__ w3,
                          bf16_t* __restrict__ wxt) {
    int tid = blockIdx.x * 256 + threadIdx.x;   // 4096*512 threads
    int k = tid >> 12;                          // 0..511
    int p = tid & 4095;
    int q = p >> 5, g = (p >> 3) & 3, jj = p & 7;
    int j = q * 8 + jj;
    const float* src = (g == 0) ? w0 : (g == 1) ? w1 : (g == 2) ? w2 : w3;
    wxt[(size_t)p * I_DIM + k] = (bf16_t)src[k * H_DIM + j];
}

__global__ void k_pack_wh(const float* __restrict__ w0, const float* __restrict__ w1,
                          const float* __restrict__ w2, const float* __restrict__ w3,
                          bf16_t* __restrict__ wht) {
    int tid = blockIdx.x * 256 + threadIdx.x;   // 4096*1024 threads
    int k = tid >> 12;                          // 0..1023
    int p = tid & 4095;
    int q = p >> 5, g = (p >> 3) & 3, jj = p & 7;
    int j = q * 8 + jj;
    const float* src = (g == 0) ? w0 : (g == 1) ? w1 : (g == 2) ? w2 : w3;
    wht[(size_t)p * H_DIM + k] = (bf16_t)src[k * H_DIM + j];
}

__global__ void k_pack_bias(const float* bi0, const float* bh0, const float* bi1, const float* bh1,
                            const float* bi2, const float* bh2, const float* bi3, const float* bh3,
                            float* __restrict__ bias) {
    int p = blockIdx.x * 256 + threadIdx.x;
    int q = p >> 5, g = (p >> 3) & 3, jj = p & 7;
    int j = q * 8 + jj;
    const float* a = (g == 0) ? bi0 : (g == 1) ? bi1 : (g == 2) ? bi2 : bi3;
    const float* b = (g == 0) ? bh0 : (g == 1) ? bh1 : (g == 2) ? bh2 : bh3;
    bias[p] = a[j] + b[j];
}

// ---------------- chunked x_proj GEMM ----------------
__global__ __launch_bounds__(256, 2) void k_xproj(
    const float* __restrict__ x, const bf16_t* __restrict__ wxt,
    const float* __restrict__ bias, bf16_t* __restrict__ xp, int r_base)
{
    __shared__ __align__(16) bf16_t Al[8 * 64 * 8];
    __shared__ __align__(16) bf16_t Bl[8 * 64 * 8];
    const int tid = threadIdx.x;
    const int n0 = blockIdx.x * 128;
    const int r0 = r_base + blockIdx.y * 128;
    const int wv = tid >> 6;
    const int lane = tid & 63;
    const int mq = wv >> 1, nq = wv & 1;
    f32x4 acc[4][4] = {};

    for (int kk = 0; kk < I_DIM; kk += 32) {
        __syncthreads();
        #pragma unroll
        for (int sidx = 0; sidx < 2; ++sidx) {
            int s = tid + sidx * 256;
            int mt = s >> 6, l = s & 63;
            int m = l & 15, kb = (l >> 4) * 8;
            int r = r0 + mt * 16 + m;
            int b = r & 63, si = r >> 6;
            const float* gp = x + ((size_t)(b * S_DIM + si)) * I_DIM + kk + kb;
            float4 v0 = *(const float4*)gp;
            float4 v1 = *(const float4*)(gp + 4);
            bf16x8 a;
            a[0] = (bf16_t)v0.x; a[1] = (bf16_t)v0.y; a[2] = (bf16_t)v0.z; a[3] = (bf16_t)v0.w;
            a[4] = (bf16_t)v1.x; a[5] = (bf16_t)v1.y; a[6] = (bf16_t)v1.z; a[7] = (bf16_t)v1.w;
            *(bf16x8*)&Al[s * 8] = a;
            bf16x8 bv = *(const bf16x8*)(wxt + (size_t)(n0 + mt * 16 + m) * I_DIM + kk + kb);
            *(bf16x8*)&Bl[s * 8] = bv;
        }
        __syncthreads();
        bf16x8 af[4], bfr[4];
        #pragma unroll
        for (int mt = 0; mt < 4; ++mt) af[mt]  = *(bf16x8*)&Al[((mq * 4 + mt) * 64 + lane) * 8];
        #pragma unroll
        for (int nt = 0; nt < 4; ++nt) bfr[nt] = *(bf16x8*)&Bl[((nq * 4 + nt) * 64 + lane) * 8];
        #pragma unroll
        for (int mt = 0; mt < 4; ++mt)
            #pragma unroll
            for (int nt = 0; nt < 4; ++nt)
                acc[mt][nt] = __builtin_amdgcn_mfma_f32_16x16x32_bf16(af[mt], bfr[nt], acc[mt][nt], 0, 0, 0);
    }
    const int l15 = lane & 15, quad = lane >> 4;
    #pragma unroll
    for (int nt = 0; nt < 4; ++nt) {
        int col = n0 + nq * 64 + nt * 16 + l15;
        float bv = bias[col];
        #pragma unroll
        for (int mt = 0; mt < 4; ++mt)
            #pragma unroll
            for (int r = 0; r < 4; ++r) {
                int row = r0 - r_base + mq * 64 + mt * 16 + quad * 4 + r;
                xp[(size_t)row * G4 + col] = (bf16_t)(acc[mt][nt][r] + bv);
            }
    }
}

// ---------------- persistent recurrent kernel (one chunk of CHUNK steps) ----------------
// 256 WGs x 64 thr. All cross-WG traffic (h, flags) via agent-scope atomics =
// sc0 sc1 write-through stores + cache-bypass loads served by LLC. NO agent
// fences in the loop (the R2 version's per-step buffer_wbl2/buffer_inv from
// 256 WGs was the 18 us/step latency wall: MfmaUtil 1.1%, all pipes idle).
__global__ __launch_bounds__(64, 1) void k_lstm(
    const bf16_t* __restrict__ wht, const bf16_t* __restrict__ xp,
    bf16_t* __restrict__ hbuf, float* __restrict__ cstbuf,
    float* __restrict__ out, unsigned* __restrict__ flags, int t0)
{
    __shared__ __align__(16) bf16_t Blds[32768];   // 64 KB B-fragments [ks(64)][lane(64)][8]
    const int lane = threadIdx.x;
    const int wg = blockIdx.x;
    const int q  = wg >> 1;
    const int bh = wg & 1;

    // Stage WhT rows q*32..+31 into LDS in 32x32x16 B-fragment order.
    for (int i = 0; i < 64; ++i) {
        int task = lane + (i << 6);
        int c = task >> 7;
        int k = (task & 127) << 3;
        bf16x8 v = *(const bf16x8*)(wht + (((size_t)(q * 32 + c)) << 10) + k);
        int base = (((k >> 4) << 6) + c + (((k >> 3) & 1) << 5)) << 3;
        *(bf16x8*)&Blds[base] = v;
    }
    __syncthreads();

    const int col  = lane & 31;
    const int ksel = lane >> 5;
    const int gt   = (lane >> 3) & 3;  // 0:i 1:f 2:g 3:o
    const int arow = bh * 32 + col;
    const int jj   = lane & 7;

    int rrow[16];
    #pragma unroll
    for (int r = 0; r < 16; ++r) rrow[r] = (r & 3) + 8 * (r >> 2) + 4 * ksel;

    float cst[16];
    if (t0 == 0) {
        #pragma unroll
        for (int r = 0; r < 16; ++r) cst[r] = 0.f;
    } else {
        #pragma unroll
        for (int r = 0; r < 16; ++r)
            cst[r] = cstbuf[(bh * 32 + rrow[r]) * H_DIM + q * 8 + jj];
    }

    bf16_t xpr[16];
    #pragma unroll
    for (int r = 0; r < 16; ++r)
        xpr[r] = xp[(size_t)(bh * 32 + rrow[r]) * G4 + q * 32 + col];

    const uint64_t* hb_u64 = (const uint64_t*)hbuf;
    uint32_t* hb_u32 = (uint32_t*)hbuf;

    for (int tl = 0; tl < CHUNK; ++tl) {
        const int t = t0 + tl;
        // A-fragment base in u64 units: buffer (t&1) is 128 KB = 16384 u64.
        const uint64_t* ap = hb_u64 + ((size_t)(t & 1) << 14) + arow * 256 + ksel * 2;

        // Pipelined LLC-bypass A-loads: 16-frag window (32 u64 in flight/lane
        // = 16 KB/CU) to stream 64 KB/CU/step from LLC at BW, not latency.
        uint64_t alo[16], ahi[16];
        #pragma unroll
        for (int j = 0; j < 16; ++j) {
            alo[j] = ld_u64_llc(ap + 4 * j);
            ahi[j] = ld_u64_llc(ap + 4 * j + 1);
        }
        f32x16 acc0 = {}, acc1 = {}, acc2 = {}, acc3 = {};
        #pragma unroll
        for (int g = 0; g < 4; ++g) {
            #pragma unroll
            for (int j = 0; j < 16; ++j) {
                u64x2 t2; t2[0] = alo[j]; t2[1] = ahi[j];
                bf16x8 a = __builtin_bit_cast(bf16x8, t2);
                if (g < 3) {
                    int ksn = (g + 1) * 16 + j;
                    alo[j] = ld_u64_llc(ap + 4 * ksn);
                    ahi[j] = ld_u64_llc(ap + 4 * ksn + 1);
                }
                int ks = g * 16 + j;
                bf16x8 b = *(const bf16x8*)&Blds[((ks << 6) + lane) << 3];
                if ((j & 3) == 0)      acc0 = __builtin_amdgcn_mfma_f32_32x32x16_bf16(a, b, acc0, 0, 0, 0);
                else if ((j & 3) == 1) acc1 = __builtin_amdgcn_mfma_f32_32x32x16_bf16(a, b, acc1, 0, 0, 0);
                else if ((j & 3) == 2) acc2 = __builtin_amdgcn_mfma_f32_32x32x16_bf16(a, b, acc2, 0, 0, 0);
                else                   acc3 = __builtin_amdgcn_mfma_f32_32x32x16_bf16(a, b, acc3, 0, 0, 0);
            }
        }
        f32x16 accs = acc0 + acc1 + acc2 + acc3;

        float act[16];
        #pragma unroll
        for (int r = 0; r < 16; ++r) {
            float pre = accs[r] + (float)xpr[r];
            act[r] = (gt == 2) ? tanh_fast(pre) : sigm(pre);
        }

        // prefetch next local step's xp (cached loads; ride through barrier in regs)
        int tln = (tl < CHUNK - 1) ? tl + 1 : tl;
        #pragma unroll
        for (int r = 0; r < 16; ++r)
            xpr[r] = xp[(size_t)(tln * 64 + bh * 32 + rrow[r]) * G4 + q * 32 + col];

        // h update: i-lanes own (row, j); write-through u32 (bf16 pair) stores.
        uint32_t* hn32 = hb_u32 + ((size_t)((t + 1) & 1) << 15);
        #pragma unroll
        for (int r = 0; r < 16; ++r) {
            float fv = __shfl_xor(act[r], 8, 64);
            float gv = __shfl_xor(act[r], 16, 64);
            float ov = __shfl_xor(act[r], 24, 64);
            if (gt == 0) {
                float cn = fv * cst[r] + act[r] * gv;
                cst[r] = cn;
                float hv = ov * tanh_fast(cn);
                float hv2 = __shfl_xor(hv, 1, 64);     // partner j within pair
                int rowg = bh * 32 + rrow[r];
                if ((jj & 1) == 0) {
                    uint32_t lo = (uint32_t)__builtin_bit_cast(uint16_t, (bf16_t)hv);
                    uint32_t hi = (uint32_t)__builtin_bit_cast(uint16_t, (bf16_t)hv2);
                    st_u32_llc(hn32 + rowg * 512 + q * 4 + (jj >> 1), lo | (hi << 16));
                }
                if (t == S_DIM - 1) {
                    int j = q * 8 + jj;
                    out[rowg * H_DIM + j] = ov * tanh_fast(cn);   // h_T
                    out[65536 + rowg * H_DIM + j] = cn;           // c_T
                }
            }
        }

        if (tl < CHUNK - 1) {
            unsigned tv = (unsigned)(t + 1);
            // Order write-through h stores at LLC before the flag; no wbl2.
            asm volatile("s_waitcnt vmcnt(0)" ::: "memory");
            __hip_atomic_store(&flags[wg], tv, __ATOMIC_RELAXED, __HIP_MEMORY_SCOPE_AGENT);
            int guard = 200000;
            for (;;) {
                unsigned f0 = __hip_atomic_load(&flags[lane],       __ATOMIC_RELAXED, __HIP_MEMORY_SCOPE_AGENT);
                unsigned f1 = __hip_atomic_load(&flags[lane + 64],  __ATOMIC_RELAXED, __HIP_MEMORY_SCOPE_AGENT);
                unsigned f2 = __hip_atomic_load(&flags[lane + 128], __ATOMIC_RELAXED, __HIP_MEMORY_SCOPE_AGENT);
                unsigned f3 = __hip_atomic_load(&flags[lane + 192], __ATOMIC_RELAXED, __HIP_MEMORY_SCOPE_AGENT);
                int ok = (f0 >= tv) && (f1 >= tv) && (f2 >= tv) && (f3 >= tv);
                if (__all(ok) || --guard == 0) break;
                __builtin_amdgcn_s_sleep(1);
            }
            __builtin_amdgcn_fence(__ATOMIC_ACQUIRE, "wavefront");  // compiler-order only; no cache ops
        }
    }

    // persist c-state for next chunk (cached stores; kernel boundary flushes)
    if (gt == 0) {
        #pragma unroll
        for (int r = 0; r < 16; ++r)
            cstbuf[(bh * 32 + rrow[r]) * H_DIM + q * 8 + jj] = cst[r];
    }
}

extern "C" void kernel_launch(void* const* d_in, const int* in_sizes, int n_in,
                              void* d_out, int out_size, void* d_ws, size_t ws_size,
                              hipStream_t stream) {
    const float* x   = (const float*)d_in[0];
    const float* wii = (const float*)d_in[1];
    const float* bii = (const float*)d_in[2];
    const float* whi = (const float*)d_in[3];
    const float* bhi = (const float*)d_in[4];
    const float* wif = (const float*)d_in[5];
    const float* bif = (const float*)d_in[6];
    const float* whf = (const float*)d_in[7];
    const float* bhf = (const float*)d_in[8];
    const float* wig = (const float*)d_in[9];
    const float* big = (const float*)d_in[10];
    const float* whg = (const float*)d_in[11];
    const float* bhg = (const float*)d_in[12];
    const float* wio = (const float*)d_in[13];
    const float* bio = (const float*)d_in[14];
    const float* who = (const float*)d_in[15];
    const float* bho = (const float*)d_in[16];

    char* ws = (char*)d_ws;
    bf16_t*  wxt   = (bf16_t*)(ws + O_WXT);
    bf16_t*  wht   = (bf16_t*)(ws + O_WHT);
    float*   bias  = (float*)(ws + O_BIAS);
    bf16_t*  hbuf  = (bf16_t*)(ws + O_HBUF);
    float*   cstb  = (float*)(ws + O_CST);
    unsigned* flags = (unsigned*)(ws + O_FLAGS);
    bf16_t*  xp    = (bf16_t*)(ws + O_XP);

    hipMemsetAsync(hbuf, 0, 2 * 64 * 1024 * sizeof(bf16_t), stream);
    hipMemsetAsync(flags, 0, 256 * sizeof(unsigned), stream);

    k_pack_wx<<<8192, 256, 0, stream>>>(wii, wif, wig, wio, wxt);
    k_pack_wh<<<16384, 256, 0, stream>>>(whi, whf, whg, who, wht);
    k_pack_bias<<<16, 256, 0, stream>>>(bii, bhi, bif, bhf, big, bhg, bio, bho, bias);

    for (int c = 0; c < NCHUNK; ++c) {
        k_xproj<<<dim3(32, CHUNK * 64 / 128), 256, 0, stream>>>(x, wxt, bias, xp, c * CHUNK * 64);
        k_lstm<<<256, 64, 0, stream>>>(wht, xp, hbuf, cstb, (float*)d_out, flags, c * CHUNK);
    }
}